// Round 3
// baseline (588.194 us; speedup 1.0000x reference)
//
#include <hip/hip_runtime.h>
#include <math.h>

typedef unsigned short u16;
using bf16x8 = __attribute__((ext_vector_type(8))) short;
using f32x4  = __attribute__((ext_vector_type(4))) float;

#define NRAYS 4096
#define NS    128
// mlp_in k-map: [0,27) app, [27,30) view, [30,192) sin(app), [192,354) cos(app),
//               [354,372) sin(view), [372,390) cos(view), zero-pad to 416
#define KPAD  416
#define KS1   13
#define KS2   4
#define H2STR 136   // plain layout for h2 (layer-3 input)

__device__ __forceinline__ u16 f2bf(float f) {
    unsigned int i = __float_as_uint(f);
    unsigned int r = (i + 0x7FFFu + ((i >> 16) & 1u)) >> 16;  // RNE
    return (u16)r;
}
__device__ __forceinline__ float bf2f(u16 u) {
    return __uint_as_float(((unsigned int)u) << 16);
}

// A-fragment-order LDS layout for a [128 x K] bf16 matrix:
//   element (m, k) -> [((k>>5)*8 + (m>>4))*64 + ((k>>3)&3)*16 + (m&15)]*8 + (k&7)
// (bijection; a wave's A-frag ds_read_b128 is lane-sequential, conflict-free)
__device__ __forceinline__ int afoff(int m, int k) {
    return ((((k >> 5) * 8 + (m >> 4)) * 64) + (((k >> 3) & 3) * 16) + (m & 15)) * 8 + (k & 7);
}

// Reorder fp32 W1/W2 into bf16 MFMA B-fragment order: value for (ks, nt, lane, j)
// is W[k = ks*32 + (lane>>4)*8 + j][n = nt*16 + (lane&15)], zero if k >= 390.
__global__ __launch_bounds__(256) void prep_kernel(
    const float* __restrict__ W1, const float* __restrict__ W2,
    u16* __restrict__ W1r, u16* __restrict__ W2r)
{
    int idx = blockIdx.x * 256 + threadIdx.x;
    if (idx < KS1 * 8 * 64 * 8) {               // 53248
        int j = idx & 7, lane = (idx >> 3) & 63, nt = (idx >> 9) & 7, ks = idx >> 12;
        int k = ks * 32 + (lane >> 4) * 8 + j;
        int n = nt * 16 + (lane & 15);
        W1r[idx] = (k < 390) ? f2bf(W1[k * 128 + n]) : (u16)0;
    } else if (idx < 53248 + 16384) {
        int i2 = idx - 53248;
        int j = i2 & 7, lane = (i2 >> 3) & 63, nt = (i2 >> 9) & 7, ks = i2 >> 12;
        int k = ks * 32 + (lane >> 4) * 8 + j;
        int n = nt * 16 + (lane & 15);
        W2r[i2] = f2bf(W2[k * 128 + n]);
    }
}

__global__ __launch_bounds__(256, 1) void render_kernel(
    const float* __restrict__ sigma_g, const float* __restrict__ app_g,
    const float* __restrict__ view_g,  const float* __restrict__ dists_g,
    const float* __restrict__ b1_g,    const float* __restrict__ b2_g,
    const float* __restrict__ w3_g,    const float* __restrict__ b3_g,
    const u16* __restrict__ w1r,       const u16* __restrict__ w2r,
    float* __restrict__ out_g)
{
    __shared__ __align__(16) u16 Xf[128 * KPAD];   // 106496 B (frag order); reused as H2
    __shared__ __align__(16) u16 H1f[128 * 128];   // 32768 B (frag order)
    __shared__ __align__(16) u16 Wbuf[2 * 4096];   // 16384 B (double-buffered W slice)
    __shared__ float b1f[128], b2f[128];
    __shared__ float w3f[384];
    __shared__ float b3f[4];
    __shared__ float alpha_s[128], scanb[128], wgt[128];
    __shared__ float red[384];

    const int tid    = threadIdx.x;
    const int r      = blockIdx.x;
    const int lane   = tid & 63;
    const int wave   = tid >> 6;
    const int lane15 = lane & 15;
    const int quad   = lane >> 4;
    const int wm     = wave >> 1;   // row half (64 rows)
    const int wn     = wave & 1;    // col half (64 cols)

    // issue W1 slice-0/1 global loads early (latency overlaps the X build)
    const uint4* w1r4 = (const uint4*)w1r;
    uint4 p0 = w1r4[tid], p1 = w1r4[tid + 256];
    uint4 n0 = w1r4[tid + 512], n1 = w1r4[tid + 768];

    // ---- stage biases / W3 ----
    if (tid < 128) { b1f[tid] = b1_g[tid]; b2f[tid] = b2_g[tid]; }
    for (int e = tid; e < 384; e += 256) w3f[e] = w3_g[e];
    if (tid < 3) b3f[tid] = b3_g[tid];

    // ---- build mlp_in X in LDS (frag order): 3840 tasks = (sample m, channel cc) ----
    const float* appR  = app_g  + r * (NS * 27);
    const float* viewR = view_g + r * (NS * 3);
    #pragma unroll 1
    for (int i = 0; i < 15; ++i) {
        int t  = tid + i * 256;
        int m  = t / 30;
        int cc = t - m * 30;
        float v; int kb_s, kb_c;
        if (cc < 27) {
            v = appR[m * 27 + cc];
            Xf[afoff(m, cc)] = f2bf(v);
            kb_s = 30 + cc * 6; kb_c = 192 + cc * 6;
        } else {
            int c = cc - 27;
            v = viewR[m * 3 + c];
            Xf[afoff(m, 27 + c)] = f2bf(v);
            kb_s = 354 + c * 6; kb_c = 372 + c * 6;
        }
        float sv = sinf(v), cv = cosf(v);
        #pragma unroll
        for (int f = 0; f < 6; ++f) {       // sin/cos(2^f * v) via exact doubling
            Xf[afoff(m, kb_s + f)] = f2bf(sv);
            Xf[afoff(m, kb_c + f)] = f2bf(cv);
            float s2 = 2.f * sv * cv;
            float c2 = cv * cv - sv * sv;
            sv = s2; cv = c2;
        }
    }
    // zero-pad k in [390, 416)
    for (int e = tid; e < 128 * 26; e += 256) {
        int m = e / 26;
        int k = 390 + (e - m * 26);
        Xf[afoff(m, k)] = 0;
    }

    // ---- alpha + transmittance ----
    if (tid < 128) {
        float x  = sigma_g[r * NS + tid] - 10.f;                 // DENSITY_SHIFT
        float sp = (x > 20.f) ? x : log1pf(expf(x));             // softplus
        float al = 1.f - expf(-sp * dists_g[r * NS + tid] * 25.f);
        if (tid == 127) al = 1.f;
        alpha_s[tid] = al;
        scanb[tid]   = 1.f - al + 1e-10f;
    }
    __syncthreads();
    // inclusive product scan (Hillis-Steele)
    for (int off = 1; off < 128; off <<= 1) {
        bool act = (tid < 128) && (tid >= off);
        float v = act ? scanb[tid - off] : 1.f;
        __syncthreads();
        if (act) scanb[tid] *= v;
        __syncthreads();
    }
    if (tid < 128) wgt[tid] = alpha_s[tid] * (tid ? scanb[tid - 1] : 1.f);

    // ---- GEMM1: h1 = relu(X @ W1 + b1) ----
    {
        uint4* d0 = (uint4*)Wbuf;
        d0[tid] = p0; d0[tid + 256] = p1;
    }
    __syncthreads();

    const f32x4 vzero = {0.f, 0.f, 0.f, 0.f};
    f32x4 acc[4][4];
    #pragma unroll
    for (int mt = 0; mt < 4; ++mt)
        #pragma unroll
        for (int nt = 0; nt < 4; ++nt) acc[mt][nt] = vzero;

    #pragma unroll 1
    for (int ks = 0; ks < KS1; ++ks) {
        const int cur = ks & 1;
        uint4 f0 = {}, f1 = {};
        if (ks + 2 < KS1) {                            // prefetch 2 ahead
            const uint4* src = w1r4 + (ks + 2) * 512;
            f0 = src[tid]; f1 = src[tid + 256];
        }
        bf16x8 a[4];
        #pragma unroll
        for (int mt = 0; mt < 4; ++mt)
            a[mt] = *(const bf16x8*)(Xf + ((ks * 8 + wm * 4 + mt) * 64 + lane) * 8);
        #pragma unroll
        for (int nt = 0; nt < 4; ++nt) {
            bf16x8 b = *(const bf16x8*)(Wbuf + cur * 4096 + ((wn * 4 + nt) * 64 + lane) * 8);
            #pragma unroll
            for (int mt = 0; mt < 4; ++mt)
                acc[mt][nt] = __builtin_amdgcn_mfma_f32_16x16x32_bf16(a[mt], b, acc[mt][nt], 0, 0, 0);
        }
        if (ks + 1 < KS1) {
            uint4* dst = (uint4*)(Wbuf + (1 - cur) * 4096);
            dst[tid] = n0; dst[tid + 256] = n1;
            n0 = f0; n1 = f1;
        }
        __syncthreads();
    }

    // epilogue 1: +b1, relu -> H1f (bf16, A-frag order)
    #pragma unroll
    for (int mt = 0; mt < 4; ++mt)
        #pragma unroll
        for (int nt = 0; nt < 4; ++nt)
            #pragma unroll
            for (int rr = 0; rr < 4; ++rr) {
                int row = wm * 64 + mt * 16 + quad * 4 + rr;
                int col = wn * 64 + nt * 16 + lane15;
                float v = acc[mt][nt][rr] + b1f[col];
                H1f[afoff(row, col)] = f2bf(fmaxf(v, 0.f));
            }
    __syncthreads();

    // ---- GEMM2: h2 = relu(h1 @ W2 + b2) ----
    const uint4* w2r4 = (const uint4*)w2r;
    {
        uint4 q0 = w2r4[tid], q1 = w2r4[tid + 256];
        uint4* d0 = (uint4*)Wbuf;
        d0[tid] = q0; d0[tid + 256] = q1;
        n0 = w2r4[tid + 512]; n1 = w2r4[tid + 768];
    }
    __syncthreads();

    f32x4 acc2[4][4];
    #pragma unroll
    for (int mt = 0; mt < 4; ++mt)
        #pragma unroll
        for (int nt = 0; nt < 4; ++nt) acc2[mt][nt] = vzero;

    #pragma unroll 1
    for (int ks = 0; ks < KS2; ++ks) {
        const int cur = ks & 1;
        uint4 f0 = {}, f1 = {};
        if (ks + 2 < KS2) {
            const uint4* src = w2r4 + (ks + 2) * 512;
            f0 = src[tid]; f1 = src[tid + 256];
        }
        bf16x8 a[4];
        #pragma unroll
        for (int mt = 0; mt < 4; ++mt)
            a[mt] = *(const bf16x8*)(H1f + ((ks * 8 + wm * 4 + mt) * 64 + lane) * 8);
        #pragma unroll
        for (int nt = 0; nt < 4; ++nt) {
            bf16x8 b = *(const bf16x8*)(Wbuf + cur * 4096 + ((wn * 4 + nt) * 64 + lane) * 8);
            #pragma unroll
            for (int mt = 0; mt < 4; ++mt)
                acc2[mt][nt] = __builtin_amdgcn_mfma_f32_16x16x32_bf16(a[mt], b, acc2[mt][nt], 0, 0, 0);
        }
        if (ks + 1 < KS2) {
            uint4* dst = (uint4*)(Wbuf + (1 - cur) * 4096);
            dst[tid] = n0; dst[tid + 256] = n1;
            n0 = f0; n1 = f1;
        }
        __syncthreads();
    }

    // epilogue 2: +b2, relu -> h2 in plain layout (stride H2STR) reusing Xf space
    u16* H2 = Xf;
    #pragma unroll
    for (int mt = 0; mt < 4; ++mt)
        #pragma unroll
        for (int nt = 0; nt < 4; ++nt)
            #pragma unroll
            for (int rr = 0; rr < 4; ++rr) {
                int row = wm * 64 + mt * 16 + quad * 4 + rr;
                int col = wn * 64 + nt * 16 + lane15;
                float v = acc2[mt][nt][rr] + b2f[col];
                H2[row * H2STR + col] = f2bf(fmaxf(v, 0.f));
            }
    __syncthreads();

    // ---- layer 3 + sigmoid + weighted accumulate ----
    if (tid < 128) {
        int s = tid;
        float a0 = b3f[0], a1 = b3f[1], a2 = b3f[2];
        #pragma unroll
        for (int kk = 0; kk < 16; ++kk) {
            bf16x8 hh = *(const bf16x8*)(H2 + s * H2STR + kk * 8);
            #pragma unroll
            for (int j = 0; j < 8; ++j) {
                float hv = bf2f((u16)hh[j]);
                int k = kk * 8 + j;
                a0 += hv * w3f[k * 3 + 0];
                a1 += hv * w3f[k * 3 + 1];
                a2 += hv * w3f[k * 3 + 2];
            }
        }
        float r0 = 1.f / (1.f + expf(-a0));
        float r1 = 1.f / (1.f + expf(-a1));
        float r2 = 1.f / (1.f + expf(-a2));
        float w = wgt[s];
        red[s]       = w * r0;
        red[128 + s] = w * r1;
        red[256 + s] = w * r2;
    }
    __syncthreads();
    for (int off = 64; off > 0; off >>= 1) {
        if (tid < off) {
            red[tid]       += red[tid + off];
            red[128 + tid] += red[128 + tid + off];
            red[256 + tid] += red[256 + tid + off];
        }
        __syncthreads();
    }
    if (tid == 0) {
        out_g[r * 3 + 0] = red[0];
        out_g[r * 3 + 1] = red[128];
        out_g[r * 3 + 2] = red[256];
    }
}

extern "C" void kernel_launch(void* const* d_in, const int* in_sizes, int n_in,
                              void* d_out, int out_size, void* d_ws, size_t ws_size,
                              hipStream_t stream) {
    (void)in_sizes; (void)n_in; (void)out_size; (void)ws_size;
    const float* sigma = (const float*)d_in[0];
    const float* app   = (const float*)d_in[1];
    const float* view  = (const float*)d_in[2];
    const float* dists = (const float*)d_in[3];
    const float* W1    = (const float*)d_in[4];
    const float* b1    = (const float*)d_in[5];
    const float* W2    = (const float*)d_in[6];
    const float* b2    = (const float*)d_in[7];
    const float* W3    = (const float*)d_in[8];
    const float* b3    = (const float*)d_in[9];
    float* out = (float*)d_out;

    u16* w1r = (u16*)d_ws;              // 53248 bf16 = 106496 B
    u16* w2r = w1r + 53248;             // 16384 bf16 =  32768 B

    prep_kernel<<<272, 256, 0, stream>>>(W1, W2, w1r, w2r);
    render_kernel<<<NRAYS, 256, 0, stream>>>(sigma, app, view, dists,
                                             b1, b2, W3, b3, w1r, w2r, out);
}

// Round 4
// 256.425 us; speedup vs baseline: 2.2938x; 2.2938x over previous
//
#include <hip/hip_runtime.h>
#include <math.h>

typedef unsigned short u16;
using bf16x8 = __attribute__((ext_vector_type(8))) short;
using f32x4  = __attribute__((ext_vector_type(4))) float;

#define NS      128
#define RAYS_PER_BLOCK 8
#define NBLOCKS (4096 / RAYS_PER_BLOCK)   // 512 = 2 blocks/CU exactly resident
#define KS1     15      // 30 channels * 16 slots = 480 K
#define NSLICE  19      // 15 (W1) + 4 (W2) unified W slices of 4096 u16
#define XS      40      // X-slice row stride in u16 (32 + 8 pad)
#define H1S     136     // h1/h2 row stride in u16 (128 + 8 pad)

// LDS pool offsets (u16 units)
#define OX0   0         // X slice buf 0: 128*40 = 5120
#define OX1   5120      // X slice buf 1
#define OW0   10240     // W buf 0: 4096
#define OW1   14336     // W buf 1
#define OH1   18432     // h1: 128*136 = 17408
#define POOLSZ 35840    // 71680 B ; h2 overlays [0, 17408)

__device__ __forceinline__ u16 f2bf(float f) {
    unsigned int i = __float_as_uint(f);
    return (u16)((i + 0x7FFFu + ((i >> 16) & 1u)) >> 16);  // RNE
}

// channel/slot -> original mlp_in k index (reference ordering)
__device__ __forceinline__ int orig_k(int ch, int slot) {
    if (ch < 27) {
        if (slot == 0) return ch;
        if (slot <= 6) return 30 + ch * 6 + (slot - 1);     // sin(app)
        return 192 + ch * 6 + (slot - 7);                    // cos(app)
    } else {
        int c = ch - 27;
        if (slot == 0) return 27 + c;
        if (slot <= 6) return 354 + c * 6 + (slot - 1);      // sin(view)
        return 372 + c * 6 + (slot - 7);                     // cos(view)
    }
}

// W1 -> 15 slices, W2 -> 4 slices, W3 -> 4 mini B-frag slices (N padded 16)
__global__ __launch_bounds__(256) void prep_kernel(
    const float* __restrict__ W1, const float* __restrict__ W2,
    const float* __restrict__ W3, u16* __restrict__ ws)
{
    int idx = blockIdx.x * 256 + threadIdx.x;
    if (idx < 61440) {                               // W1r: [ks15][nt8][lane64][j8]
        int j = idx & 7, lane = (idx >> 3) & 63, nt = (idx >> 9) & 7, ks = idx >> 12;
        int q = lane >> 4, l15 = lane & 15;
        int klocal = q * 8 + j;                      // 0..31
        int ch = ks * 2 + (klocal >> 4);
        int slot = klocal & 15;
        int n = nt * 16 + l15;
        ws[idx] = (slot < 13) ? f2bf(W1[orig_k(ch, slot) * 128 + n]) : (u16)0;
    } else if (idx < 77824) {                        // W2r: [ks4][nt8][lane64][j8]
        int i2 = idx - 61440;
        int j = i2 & 7, lane = (i2 >> 3) & 63, nt = (i2 >> 9) & 7, ks = i2 >> 12;
        int k = ks * 32 + (lane >> 4) * 8 + j;
        int n = nt * 16 + (lane & 15);
        ws[idx] = f2bf(W2[k * 128 + n]);
    } else if (idx < 79872) {                        // W3r: [ks4][lane64][j8], N pad 16
        int i3 = idx - 77824;
        int j = i3 & 7, lane = (i3 >> 3) & 63, ks = i3 >> 9;
        int k = ks * 32 + (lane >> 4) * 8 + j;
        int n = lane & 15;
        ws[idx] = (n < 3) ? f2bf(W3[k * 3 + n]) : (u16)0;
    }
}

__global__ __launch_bounds__(256, 2) void render_kernel(
    const float* __restrict__ sigma_g, const float* __restrict__ app_g,
    const float* __restrict__ view_g,  const float* __restrict__ dists_g,
    const float* __restrict__ b1_g,    const float* __restrict__ b2_g,
    const float* __restrict__ b3_g,    const u16* __restrict__ ws,
    float* __restrict__ out_g)
{
    __shared__ __align__(16) u16 pool[POOLSZ];
    __shared__ float scanS;          // wave0 scan total broadcast
    __shared__ float part[NS * 3];   // per-sample rgb (pre-weight)
    __shared__ float sum2[6];        // per-wave final partials

    const int tid  = threadIdx.x;
    const int lane = tid & 63;
    const int wave = tid >> 6;
    const int l15  = lane & 15;
    const int quad = lane >> 4;
    const int wm   = wave >> 1;      // row half
    const int wn   = wave & 1;       // col half

    const u16* w1r = ws;             // 15 slices * 4096
    const u16* w3r = ws + 77824;

    // per-kernel constants in registers
    float b1r[4], b2r[4];
    #pragma unroll
    for (int nt = 0; nt < 4; ++nt) {
        int col = wn * 64 + nt * 16 + l15;
        b1r[nt] = b1_g[col];
        b2r[nt] = b2_g[col];
    }
    const float b3v = (l15 < 3) ? b3_g[l15] : 0.f;
    bf16x8 w3fr[4];
    #pragma unroll
    for (int ks = 0; ks < 4; ++ks)
        w3fr[ks] = *(const bf16x8*)(w3r + (ks * 64 + lane) * 8);

    const int m_b  = tid >> 1;       // X-build row
    const int cl_b = tid & 1;        // X-build channel-local

    #pragma unroll 1
    for (int ri = 0; ri < RAYS_PER_BLOCK; ++ri) {
        const int r  = blockIdx.x * RAYS_PER_BLOCK + ri;
        const int rb = r * NS;

        // ---- W slice 0/1 prefetch (regs) ----
        const uint4* wsl = (const uint4*)w1r;
        uint4 na = wsl[tid], nb = wsl[tid + 256];            // slice 0
        uint4 pa = wsl[tid + 512], pb = wsl[tid + 768];      // slice 1

        // ---- alpha + shuffle transmittance scan (waves 0,1) ----
        float alpha = 0.f, prod = 1.f, wr = 0.f;
        if (tid < NS) {
            float x  = sigma_g[rb + tid] - 10.f;
            float sp = (x > 20.f) ? x : log1pf(expf(x));
            alpha = 1.f - expf(-sp * dists_g[rb + tid] * 25.f);
            if (tid == NS - 1) alpha = 1.f;
            float tb = 1.f - alpha + 1e-10f;
            prod = tb;
            #pragma unroll
            for (int d = 1; d < 64; d <<= 1) {
                float v = __shfl_up(prod, d);
                if (lane >= d) prod *= v;
            }
            if (tid == 63) scanS = prod;
        }

        // ---- build X slice 0 (channels 0,1) ----
        {
            u16* Xb = pool + OX0;
            float v = (float)app_g[(rb + m_b) * 27 + cl_b];   // ch = cl_b < 27
            float rev = v * 0.15915494309189535f;
            rev -= floorf(rev);
            float sv = __builtin_amdgcn_sinf(rev);
            float cv = __builtin_amdgcn_cosf(rev);
            bf16x8 lo, hi;
            lo[0] = (short)f2bf(v);
            #pragma unroll
            for (int f = 0; f < 6; ++f) {
                if (f < 5) { lo[1 + f] = (short)f2bf(sv); }
                else       { lo[6] = (short)f2bf(sv); }
                if (f == 0) lo[7] = (short)f2bf(cv);
                else        hi[f - 1] = (short)f2bf(cv);
                float s2 = 2.f * sv * cv, c2 = cv * cv - sv * sv;
                sv = s2; cv = c2;
            }
            hi[5] = 0; hi[6] = 0; hi[7] = 0;
            *(bf16x8*)(Xb + m_b * XS + cl_b * 16)     = lo;
            *(bf16x8*)(Xb + m_b * XS + cl_b * 16 + 8) = hi;
        }
        // stage W slice 0
        { uint4* d = (uint4*)(pool + OW0); d[tid] = na; d[tid + 256] = nb; }
        na = pa; nb = pb;
        __syncthreads();

        // finish weights: wr = alpha * T_exclusive
        if (tid < NS) {
            float prev = __shfl_up(prod, 1);
            float base = (lane == 0) ? 1.f : prev;
            float scale = (wave == 1) ? scanS : 1.f;
            wr = alpha * base * scale;
        }

        // ---- unified 19-slice K-loop: GEMM1 (0..14) + GEMM2 (15..18) ----
        const f32x4 vzero = {0.f, 0.f, 0.f, 0.f};
        f32x4 acc[4][4];
        #pragma unroll
        for (int mt = 0; mt < 4; ++mt)
            #pragma unroll
            for (int nt = 0; nt < 4; ++nt) acc[mt][nt] = vzero;

        #pragma unroll 1
        for (int i = 0; i < NSLICE; ++i) {
            uint4 fa = {}, fb = {};
            if (i + 2 < NSLICE) {                    // 2-deep prefetch
                const uint4* src = (const uint4*)(ws + (i + 2) * 4096);
                fa = src[tid]; fb = src[tid + 256];
            }
            const u16* Wb = pool + (((i & 1) == 0) ? OW0 : OW1);
            bf16x8 a[4];
            if (i < KS1) {
                const u16* Xb = pool + (((i & 1) == 0) ? OX0 : OX1);
                #pragma unroll
                for (int mt = 0; mt < 4; ++mt)
                    a[mt] = *(const bf16x8*)(Xb + (wm * 64 + mt * 16 + l15) * XS + quad * 8);
            } else {
                const int i2 = i - KS1;
                #pragma unroll
                for (int mt = 0; mt < 4; ++mt)
                    a[mt] = *(const bf16x8*)(pool + OH1 +
                             (wm * 64 + mt * 16 + l15) * H1S + i2 * 32 + quad * 8);
            }
            #pragma unroll
            for (int nt = 0; nt < 4; ++nt) {
                bf16x8 b = *(const bf16x8*)(Wb + ((wn * 4 + nt) * 64 + lane) * 8);
                #pragma unroll
                for (int mt = 0; mt < 4; ++mt)
                    acc[mt][nt] = __builtin_amdgcn_mfma_f32_16x16x32_bf16(a[mt], b, acc[mt][nt], 0, 0, 0);
            }
            if (i < KS1 - 1) {                       // build X slice i+1 (ch 2i+2, 2i+3)
                u16* Xb = pool + ((((i + 1) & 1) == 0) ? OX0 : OX1);
                int ch = 2 * (i + 1) + cl_b;
                float v = (ch < 27) ? app_g[(rb + m_b) * 27 + ch]
                                    : view_g[(rb + m_b) * 3 + (ch - 27)];
                float rev = v * 0.15915494309189535f;
                rev -= floorf(rev);
                float sv = __builtin_amdgcn_sinf(rev);
                float cv = __builtin_amdgcn_cosf(rev);
                bf16x8 lo, hi;
                lo[0] = (short)f2bf(v);
                #pragma unroll
                for (int f = 0; f < 6; ++f) {
                    lo[1 + f] = (short)f2bf(sv);
                    if (f == 0) lo[7] = (short)f2bf(cv);
                    else        hi[f - 1] = (short)f2bf(cv);
                    float s2 = 2.f * sv * cv, c2 = cv * cv - sv * sv;
                    sv = s2; cv = c2;
                }
                // note: lo[7] must be cos f0; slot6 = sin f5 -> fix ordering:
                // slots: [0]=v [1..6]=sin f0..5 [7..12]=cos f0..5
                hi[5] = 0; hi[6] = 0; hi[7] = 0;
                *(bf16x8*)(Xb + m_b * XS + cl_b * 16)     = lo;
                *(bf16x8*)(Xb + m_b * XS + cl_b * 16 + 8) = hi;
            }
            if (i == KS1 - 1) {
                // epilogue 1: h1 = relu(acc + b1) -> H1 (row-major, stride 136)
                #pragma unroll
                for (int mt = 0; mt < 4; ++mt)
                    #pragma unroll
                    for (int nt = 0; nt < 4; ++nt) {
                        int col = wn * 64 + nt * 16 + l15;
                        #pragma unroll
                        for (int rr = 0; rr < 4; ++rr) {
                            int row = wm * 64 + mt * 16 + quad * 4 + rr;
                            float v = acc[mt][nt][rr] + b1r[nt];
                            pool[OH1 + row * H1S + col] = f2bf(fmaxf(v, 0.f));
                        }
                        acc[mt][nt] = vzero;          // reset for GEMM2
                    }
            }
            if (i + 1 < NSLICE) {                    // stage W slice i+1
                uint4* d = (uint4*)(pool + ((((i + 1) & 1) == 0) ? OW0 : OW1));
                d[tid] = na; d[tid + 256] = nb;
            }
            na = fa; nb = fb;
            __syncthreads();
        }

        // ---- epilogue 2: h2 = relu(acc + b2) -> H2 overlaying pool[0..) ----
        #pragma unroll
        for (int mt = 0; mt < 4; ++mt)
            #pragma unroll
            for (int nt = 0; nt < 4; ++nt) {
                int col = wn * 64 + nt * 16 + l15;
                #pragma unroll
                for (int rr = 0; rr < 4; ++rr) {
                    int row = wm * 64 + mt * 16 + quad * 4 + rr;
                    float v = acc[mt][nt][rr] + b2r[nt];
                    pool[row * H1S + col] = f2bf(fmaxf(v, 0.f));
                }
            }
        __syncthreads();

        // ---- layer 3 via MFMA: rgb = sigmoid(h2 @ W3 + b3) ----
        f32x4 acc3[2] = {vzero, vzero};
        #pragma unroll
        for (int mi = 0; mi < 2; ++mi) {
            int mtt = wn * 2 + mi;                   // waves split the 4 row-tiles
            #pragma unroll
            for (int ks = 0; ks < 4; ++ks) {
                bf16x8 a3 = *(const bf16x8*)(pool +
                    (wm * 64 + mtt * 16 + l15) * H1S + ks * 32 + quad * 8);
                acc3[mi] = __builtin_amdgcn_mfma_f32_16x16x32_bf16(a3, w3fr[ks], acc3[mi], 0, 0, 0);
            }
        }
        if (l15 < 3) {
            #pragma unroll
            for (int mi = 0; mi < 2; ++mi) {
                int mtt = wn * 2 + mi;
                #pragma unroll
                for (int rr = 0; rr < 4; ++rr) {
                    int row = wm * 64 + mtt * 16 + quad * 4 + rr;
                    float v = acc3[mi][rr] + b3v;
                    part[row * 3 + l15] = 1.f / (1.f + expf(-v));
                }
            }
        }
        __syncthreads();

        // ---- weighted sum over samples ----
        float v0 = 0.f, v1 = 0.f, v2 = 0.f;
        if (tid < NS) {
            v0 = wr * part[tid * 3 + 0];
            v1 = wr * part[tid * 3 + 1];
            v2 = wr * part[tid * 3 + 2];
            #pragma unroll
            for (int d = 1; d < 64; d <<= 1) {
                v0 += __shfl_xor(v0, d);
                v1 += __shfl_xor(v1, d);
                v2 += __shfl_xor(v2, d);
            }
            if (lane == 0) {
                sum2[wave * 3 + 0] = v0;
                sum2[wave * 3 + 1] = v1;
                sum2[wave * 3 + 2] = v2;
            }
        }
        __syncthreads();
        if (tid == 0) {
            out_g[r * 3 + 0] = sum2[0] + sum2[3];
            out_g[r * 3 + 1] = sum2[1] + sum2[4];
            out_g[r * 3 + 2] = sum2[2] + sum2[5];
        }
        __syncthreads();
    }
}

extern "C" void kernel_launch(void* const* d_in, const int* in_sizes, int n_in,
                              void* d_out, int out_size, void* d_ws, size_t ws_size,
                              hipStream_t stream) {
    (void)in_sizes; (void)n_in; (void)out_size; (void)ws_size;
    const float* sigma = (const float*)d_in[0];
    const float* app   = (const float*)d_in[1];
    const float* view  = (const float*)d_in[2];
    const float* dists = (const float*)d_in[3];
    const float* W1    = (const float*)d_in[4];
    const float* b1    = (const float*)d_in[5];
    const float* W2    = (const float*)d_in[6];
    const float* b2    = (const float*)d_in[7];
    const float* W3    = (const float*)d_in[8];
    const float* b3    = (const float*)d_in[9];
    float* out = (float*)d_out;

    u16* ws = (u16*)d_ws;   // 61440 (W1r) + 16384 (W2r) + 2048 (W3r) u16 = 159744 B

    prep_kernel<<<312, 256, 0, stream>>>(W1, W2, W3, ws);
    render_kernel<<<NBLOCKS, 256, 0, stream>>>(sigma, app, view, dists,
                                               b1, b2, b3, ws, out);
}